// Round 11
// baseline (674.040 us; speedup 1.0000x reference)
//
#include <hip/hip_runtime.h>

#define BB 512
#define TT 1024
#define II 50
#define HH 32
#define CH 16            // steps per chunk (barrier cadence; = MFMA M)
#define NCH (TT / CH)    // 64 chunks
#define RSLOT 32         // ring slots = 2 chunks (double buffer)

typedef float v2f __attribute__((ext_vector_type(2)));
typedef float v4f __attribute__((ext_vector_type(4)));
typedef short v8s __attribute__((ext_vector_type(8)));        // 8 bf16
typedef _Float16 v2h __attribute__((ext_vector_type(2)));     // half2

__device__ __forceinline__ float fast_rcp(float x) { return __builtin_amdgcn_rcpf(x); }
__device__ __forceinline__ float sigm(float x) { return fast_rcp(1.f + __expf(-x)); }
__device__ __forceinline__ float tanh_(float x) {
    return 1.f - 2.f * fast_rcp(1.f + __expf(2.f * x));   // saturates correctly
}
__device__ __forceinline__ short bf16rne(float f) {      // fp32 -> bf16 RNE
    unsigned u = __float_as_uint(f);
    u += 0x7FFF + ((u >> 16) & 1);
    return (short)(u >> 16);
}
__device__ __forceinline__ v2h asv2h(int v) { return __builtin_bit_cast(v2h, v); }

// d_out is poisoned before every launch: init every element to the combined
// FC bias b_comb = fc3_w @ fc1_b + fc3_b (fc1->fc3 is affine-affine; dropout
// is identity in eval). The scan kernel atomicAdds partial dots on top.
__global__ void init_out_kernel(float* __restrict__ out,
                                const float* __restrict__ fc1_b,
                                const float* __restrict__ fc3_w,
                                const float* __restrict__ fc3_b,
                                int n) {
    int idx = blockIdx.x * blockDim.x + threadIdx.x;
    float b = fc3_b[0];
    #pragma unroll
    for (int k = 0; k < 64; ++k) b += fc3_w[k] * fc1_b[k];
    if (idx < n) out[idx] = b;
}

// One workgroup (128 threads = 2 waves) per PAIR OF BATCHES (both dirs).
//   wave 0 = CONSUMER: lanes 0-31 fwd, lanes 32-63 rev; lane owns all 4
//            gates of one hidden unit for BOTH batches. The step body fuses
//            batch A and batch B (loads together, dots together, stores
//            together, ONE fence per pair) so the two independent chains
//            fill each other's LDS-roundtrip and dot-latency stalls —
//            round-10 showed the consumer is chain-latency-bound, not
//            issue-bound, with 1 wave/SIMD.
//   wave 1 = PRODUCER: ih projection for both batches x dirs via bf16 MFMA
//            (64 MFMA / 16-step chunk), plus deferred-FC flush + atomicAdd.
// Ring is fp16 (halves LDS so 2 batches fit): [slot][batch][dir][128],
//   cidx: i_k->2k, f_k->2k+1, g_k->64+2k, o_k->64+2k+1 -> consumer reads two
//   b32 half2s per batch-step, PRELOADED per 8-step half-chunk.
// Bias seeded in the consumer's accumulators (MFMA output is biasless).
// MFMA layouts (guide-verified m89/m118/m120):
//   A (16x32): m=lane&15, k=(lane>>4)*8+j ; B (32x16): n=lane&15, same k
//   D (16x16): m=(lane>>4)*4+reg, n=lane&15
// CRITICAL (round-6 lesson): empty asm memory clobber at the end of each
// fused step-pair pins the hst store->load order across unrolled steps.
__global__ void __launch_bounds__(128, 1) lstm_pc_kernel(
    const float* __restrict__ x,
    const float* __restrict__ w_ih_f, const float* __restrict__ w_hh_f,
    const float* __restrict__ b_ih_f, const float* __restrict__ b_hh_f,
    const float* __restrict__ w_ih_r, const float* __restrict__ w_hh_r,
    const float* __restrict__ b_ih_r, const float* __restrict__ b_hh_r,
    const float* __restrict__ fc1_w, const float* __restrict__ fc3_w,
    float* __restrict__ out)
{
    __shared__ _Float16 ringH[RSLOT * 512];     // 32 KB: fp16 gate projections
    __shared__ float hbuf[2][2][HH][33];        // 16.9 KB: deferred FC partials
    __shared__ __align__(16) _Float16 hsth[2][64]; // 256 B: h(t-1), per batch

    const int tid  = threadIdx.x;
    const int lane = tid & 63;
    const int wave = tid >> 6;            // 0 consumer, 1 producer
    const int bp   = blockIdx.x;          // batch pair
    const float* xb[2]  = {x + (size_t)(2 * bp) * TT * II,
                           x + (size_t)(2 * bp + 1) * TT * II};
    float* outp[2] = {out + (size_t)(2 * bp) * TT,
                      out + (size_t)(2 * bp + 1) * TT};

    if (wave == 1) {
        // ========== PRODUCER (MFMA ih projection, 2 batches x 2 dirs) ======
        const int nl = lane & 15;         // A: m / B: n / D: n
        const int q  = lane >> 4;         // quad 0..3
        const float* wih[2] = {w_ih_f, w_ih_r};

        // B fragments (persistent, shared across batches): Bf[d][nt][kf]
        v8s Bf[2][8][2];
        #pragma unroll
        for (int d = 0; d < 2; ++d)
            #pragma unroll
            for (int nt = 0; nt < 8; ++nt) {
                const int n = nt * 16 + nl;
                #pragma unroll
                for (int kf = 0; kf < 2; ++kf)
                    #pragma unroll
                    for (int j = 0; j < 8; ++j) {
                        const int k = kf * 32 + q * 8 + j;
                        Bf[d][nt][kf][j] = (k < II) ? bf16rne(wih[d][n * II + k])
                                                    : (short)0;
                    }
            }

        // gate g -> interleaved ring column
        auto cidx = [](int g) -> int {
            return (g < 32) ? 2 * g
                 : (g < 64) ? 2 * (g - 32) + 1
                 : (g < 96) ? 64 + 2 * (g - 64)
                            : 64 + 2 * (g - 96) + 1;
        };

        auto produce_chunk = [&](int c) {
            #pragma unroll
            for (int bb = 0; bb < 2; ++bb)
                #pragma unroll
                for (int d = 0; d < 2; ++d) {
                    const int S = c * CH + nl;         // this lane's A-row step
                    const int t = d ? (TT - 1 - S) : S;
                    const float* xr = xb[bb] + (size_t)t * II;
                    v8s A0, A1;
                    #pragma unroll
                    for (int j = 0; j < 8; ++j) A0[j] = bf16rne(xr[q * 8 + j]);
                    #pragma unroll
                    for (int j = 0; j < 8; ++j) {
                        const int k = 32 + q * 8 + j;
                        A1[j] = (k < II) ? bf16rne(xr[k]) : (short)0;
                    }
                    #pragma unroll
                    for (int nt = 0; nt < 8; ++nt) {
                        v4f acc = {0.f, 0.f, 0.f, 0.f};
                        acc = __builtin_amdgcn_mfma_f32_16x16x32_bf16(A0, Bf[d][nt][0], acc, 0, 0, 0);
                        acc = __builtin_amdgcn_mfma_f32_16x16x32_bf16(A1, Bf[d][nt][1], acc, 0, 0, 0);
                        const int col = bb * 256 + d * 128 + cidx(nt * 16 + nl);
                        #pragma unroll
                        for (int r = 0; r < 4; ++r) {
                            const int slot = (c * CH + q * 4 + r) & (RSLOT - 1);
                            ringH[slot * 512 + col] = (_Float16)acc[r];
                        }
                    }
                }
        };
        // flush chunk m: 16 outputs per (batch,dir) -> 64 lanes, one each
        auto flush = [&](int m) {
            const int bb  = lane >> 5;
            const int dd  = (lane >> 4) & 1;
            const int idx = lane & 15;
            const int ti  = m * CH + idx;
            const int col = ti & 31;
            float d0 = 0.f, d1 = 0.f, d2 = 0.f, d3 = 0.f;
            #pragma unroll
            for (int k = 0; k < HH; k += 4) {
                d0 += hbuf[bb][dd][k    ][col];
                d1 += hbuf[bb][dd][k + 1][col];
                d2 += hbuf[bb][dd][k + 2][col];
                d3 += hbuf[bb][dd][k + 3][col];
            }
            const int t = dd ? (TT - 1 - ti) : ti;
            atomicAdd(&outp[bb][t], (d0 + d1) + (d2 + d3));
        };

        produce_chunk(0);
        __syncthreads();
        for (int n = 0; n < NCH; ++n) {
            if (n + 1 < NCH) produce_chunk(n + 1);
            if (n >= 1) flush(n - 1);
            __syncthreads();
        }
        flush(NCH - 1);
    } else {
        // ===== CONSUMER (recurrence, 2 batches interleaved, fdot2) =========
        const int d = lane >> 5;          // 0 fwd (lanes 0-31), 1 rev
        const int k = lane & 31;          // hidden unit
        const float* w_hh = d ? w_hh_r : w_hh_f;
        const float* bi   = d ? b_ih_r : b_ih_f;
        const float* bh   = d ? b_hh_r : b_hh_f;

        // fp16 K-packed weight pairs (shared by both batches)
        v2h wph[4][16];
        float bias4[4];
        #pragma unroll
        for (int D = 0; D < 4; ++D) {
            const int row = D * 32 + k;
            #pragma unroll
            for (int j = 0; j < 16; ++j) {
                wph[D][j].x = (_Float16)w_hh[row * HH + 2 * j];
                wph[D][j].y = (_Float16)w_hh[row * HH + 2 * j + 1];
            }
            bias4[D] = bi[row] + bh[row];
        }

        // fused FC weight for hidden unit j = d*32 + k (shared by batches)
        float wc = 0.f;
        {
            const int j = d * HH + k;
            #pragma unroll
            for (int n = 0; n < 64; ++n) wc += fc3_w[n] * fc1_w[n * 64 + j];
        }

        hsth[0][lane] = (_Float16)0.f;    // h(-1) = 0 (same-wave in-order DS)
        hsth[1][lane] = (_Float16)0.f;
        float cA = 0.f, cB = 0.f;

        __syncthreads();                  // matches producer's prologue barrier

        for (int n = 0; n < NCH; ++n) {
            const int slot0 = (n & 1) * CH;
            const int col0  = (n & 1) * CH;
            #pragma unroll
            for (int half = 0; half < 2; ++half) {
                // preload 8 steps x 2 batches x 2 half2s (off-chain)
                int pA1[8], pA2[8], pB1[8], pB2[8];
                #pragma unroll
                for (int u = 0; u < 8; ++u) {
                    const int base = (slot0 + half * 8 + u) * 512 + d * 128 + 2 * k;
                    pA1[u] = *(const int*)&ringH[base];
                    pA2[u] = *(const int*)&ringH[base + 64];
                    pB1[u] = *(const int*)&ringH[base + 256];
                    pB2[u] = *(const int*)&ringH[base + 256 + 64];
                }
                #pragma unroll
                for (int u = 0; u < 8; ++u) {
                    // ---- fused step-pair: batch A and B interleaved ----
                    int4 aw0 = *(const int4*)&hsth[0][d * 32];
                    int4 aw1 = *(const int4*)&hsth[0][d * 32 + 8];
                    int4 aw2 = *(const int4*)&hsth[0][d * 32 + 16];
                    int4 aw3 = *(const int4*)&hsth[0][d * 32 + 24];
                    int4 bw0 = *(const int4*)&hsth[1][d * 32];
                    int4 bw1 = *(const int4*)&hsth[1][d * 32 + 8];
                    int4 bw2 = *(const int4*)&hsth[1][d * 32 + 16];
                    int4 bw3 = *(const int4*)&hsth[1][d * 32 + 24];

                    float zAa[4], zBa[4], zAb[4], zBb[4];
                    #pragma unroll
                    for (int D = 0; D < 4; ++D) {
                        zAa[D] = bias4[D]; zBa[D] = 0.f;
                        zAb[D] = bias4[D]; zBb[D] = 0.f;
                    }
                    #pragma unroll
                    for (int D = 0; D < 4; ++D) {
                        zAa[D] = __builtin_amdgcn_fdot2(asv2h(aw0.x), wph[D][0],  zAa[D], false);
                        zAb[D] = __builtin_amdgcn_fdot2(asv2h(bw0.x), wph[D][0],  zAb[D], false);
                        zBa[D] = __builtin_amdgcn_fdot2(asv2h(aw0.y), wph[D][1],  zBa[D], false);
                        zBb[D] = __builtin_amdgcn_fdot2(asv2h(bw0.y), wph[D][1],  zBb[D], false);
                        zAa[D] = __builtin_amdgcn_fdot2(asv2h(aw0.z), wph[D][2],  zAa[D], false);
                        zAb[D] = __builtin_amdgcn_fdot2(asv2h(bw0.z), wph[D][2],  zAb[D], false);
                        zBa[D] = __builtin_amdgcn_fdot2(asv2h(aw0.w), wph[D][3],  zBa[D], false);
                        zBb[D] = __builtin_amdgcn_fdot2(asv2h(bw0.w), wph[D][3],  zBb[D], false);
                        zAa[D] = __builtin_amdgcn_fdot2(asv2h(aw1.x), wph[D][4],  zAa[D], false);
                        zAb[D] = __builtin_amdgcn_fdot2(asv2h(bw1.x), wph[D][4],  zAb[D], false);
                        zBa[D] = __builtin_amdgcn_fdot2(asv2h(aw1.y), wph[D][5],  zBa[D], false);
                        zBb[D] = __builtin_amdgcn_fdot2(asv2h(bw1.y), wph[D][5],  zBb[D], false);
                        zAa[D] = __builtin_amdgcn_fdot2(asv2h(aw1.z), wph[D][6],  zAa[D], false);
                        zAb[D] = __builtin_amdgcn_fdot2(asv2h(bw1.z), wph[D][6],  zAb[D], false);
                        zBa[D] = __builtin_amdgcn_fdot2(asv2h(aw1.w), wph[D][7],  zBa[D], false);
                        zBb[D] = __builtin_amdgcn_fdot2(asv2h(bw1.w), wph[D][7],  zBb[D], false);
                        zAa[D] = __builtin_amdgcn_fdot2(asv2h(aw2.x), wph[D][8],  zAa[D], false);
                        zAb[D] = __builtin_amdgcn_fdot2(asv2h(bw2.x), wph[D][8],  zAb[D], false);
                        zBa[D] = __builtin_amdgcn_fdot2(asv2h(aw2.y), wph[D][9],  zBa[D], false);
                        zBb[D] = __builtin_amdgcn_fdot2(asv2h(bw2.y), wph[D][9],  zBb[D], false);
                        zAa[D] = __builtin_amdgcn_fdot2(asv2h(aw2.z), wph[D][10], zAa[D], false);
                        zAb[D] = __builtin_amdgcn_fdot2(asv2h(bw2.z), wph[D][10], zAb[D], false);
                        zBa[D] = __builtin_amdgcn_fdot2(asv2h(aw2.w), wph[D][11], zBa[D], false);
                        zBb[D] = __builtin_amdgcn_fdot2(asv2h(bw2.w), wph[D][11], zBb[D], false);
                        zAa[D] = __builtin_amdgcn_fdot2(asv2h(aw3.x), wph[D][12], zAa[D], false);
                        zAb[D] = __builtin_amdgcn_fdot2(asv2h(bw3.x), wph[D][12], zAb[D], false);
                        zBa[D] = __builtin_amdgcn_fdot2(asv2h(aw3.y), wph[D][13], zBa[D], false);
                        zBb[D] = __builtin_amdgcn_fdot2(asv2h(bw3.y), wph[D][13], zBb[D], false);
                        zAa[D] = __builtin_amdgcn_fdot2(asv2h(aw3.z), wph[D][14], zAa[D], false);
                        zAb[D] = __builtin_amdgcn_fdot2(asv2h(bw3.z), wph[D][14], zAb[D], false);
                        zBa[D] = __builtin_amdgcn_fdot2(asv2h(aw3.w), wph[D][15], zBa[D], false);
                        zBb[D] = __builtin_amdgcn_fdot2(asv2h(bw3.w), wph[D][15], zBb[D], false);
                    }
                    const v2h pifA = asv2h(pA1[u]), pgoA = asv2h(pA2[u]);
                    const v2h pifB = asv2h(pB1[u]), pgoB = asv2h(pB2[u]);
                    const float ziA = (float)pifA.x + (zAa[0] + zBa[0]);
                    const float zfA = (float)pifA.y + (zAa[1] + zBa[1]);
                    const float zgA = (float)pgoA.x + (zAa[2] + zBa[2]);
                    const float zoA = (float)pgoA.y + (zAa[3] + zBa[3]);
                    const float ziB = (float)pifB.x + (zAb[0] + zBb[0]);
                    const float zfB = (float)pifB.y + (zAb[1] + zBb[1]);
                    const float zgB = (float)pgoB.x + (zAb[2] + zBb[2]);
                    const float zoB = (float)pgoB.y + (zAb[3] + zBb[3]);

                    const float giA = sigm(ziA), gfA = sigm(zfA);
                    const float ggA = tanh_(zgA), goA = sigm(zoA);
                    const float giB = sigm(ziB), gfB = sigm(zfB);
                    const float ggB = tanh_(zgB), goB = sigm(zoB);

                    cA = fmaf(gfA, cA, giA * ggA);
                    cB = fmaf(gfB, cB, giB * ggB);
                    const float hA = goA * tanh_(cA);
                    const float hB = goB * tanh_(cB);

                    hsth[0][lane] = (_Float16)hA;
                    hsth[1][lane] = (_Float16)hB;
                    const int col = col0 + half * 8 + u;
                    hbuf[0][d][k][col] = hA * wc;
                    hbuf[1][d][k][col] = hB * wc;
                    // ordering fence (round-6 lesson): stores may not sink,
                    // next pair's loads may not hoist. Zero insts emitted.
                    asm volatile("" ::: "memory");
                }
            }
            __syncthreads();
        }
    }
}

extern "C" void kernel_launch(void* const* d_in, const int* in_sizes, int n_in,
                              void* d_out, int out_size, void* d_ws, size_t ws_size,
                              hipStream_t stream) {
    const float* x      = (const float*)d_in[0];
    const float* w_ih_f = (const float*)d_in[1];
    const float* w_hh_f = (const float*)d_in[2];
    const float* b_ih_f = (const float*)d_in[3];
    const float* b_hh_f = (const float*)d_in[4];
    const float* w_ih_r = (const float*)d_in[5];
    const float* w_hh_r = (const float*)d_in[6];
    const float* b_ih_r = (const float*)d_in[7];
    const float* b_hh_r = (const float*)d_in[8];
    const float* fc1_w  = (const float*)d_in[9];
    const float* fc1_b  = (const float*)d_in[10];
    const float* fc3_w  = (const float*)d_in[11];
    const float* fc3_b  = (const float*)d_in[12];
    float* out = (float*)d_out;

    const int n = BB * TT;
    init_out_kernel<<<(n + 255) / 256, 256, 0, stream>>>(out, fc1_b, fc3_w, fc3_b, n);

    // 256 workgroups = batch pairs; 2 waves each (consumer + producer).
    lstm_pc_kernel<<<BB / 2, 128, 0, stream>>>(
        x, w_ih_f, w_hh_f, b_ih_f, b_hh_f,
        w_ih_r, w_hh_r, b_ih_r, b_hh_r,
        fc1_w, fc3_w, out);
}